// Round 13
// baseline (473.924 us; speedup 1.0000x reference)
//
#include <hip/hip_runtime.h>

typedef unsigned short u16;
typedef unsigned int u32;
typedef __attribute__((ext_vector_type(8))) short bf16x8;
typedef __attribute__((ext_vector_type(4))) float f32x4;
typedef __attribute__((ext_vector_type(2))) float f32x2;

#define NN 50000
#define NE 640000

// ---- bf16 helpers (bf16 -> f32 exact: shift<<16; f32 -> bf16 RNE) ----
__device__ __forceinline__ float bfl(u32 u) { return __uint_as_float(u << 16); }
__device__ __forceinline__ float bfh(u32 u) { return __uint_as_float(u & 0xffff0000u); }
__device__ __forceinline__ float bf1(u16 v) { return __uint_as_float(((u32)v) << 16); }
__device__ __forceinline__ u16 f2bf(float f) {
  u32 u = __float_as_uint(f);
  u32 r = (u + 0x7fffu + ((u >> 16) & 1u)) >> 16;
  return (u16)r;
}

__device__ __forceinline__ f32x2 bc2(float s) { return (f32x2){s, s}; }
__device__ __forceinline__ f32x2 pkfma(f32x2 a, f32x2 b, f32x2 c) {
  return __builtin_elementwise_fma(a, b, c);  // -> v_pk_fma_f32 on CDNA
}
__device__ __forceinline__ f32x2 pkabs(f32x2 a) {
  return __builtin_elementwise_abs(a);
}

// DPP-based partial butterfly add (VALU pipe). All row-scoped (<=16 lanes):
// xor1 = quad_perm 0xB1; xor2 = quad_perm 0x4E; i^7-in-8 = row_half_mirror
// 0x141; i^15-in-16 = row_mirror 0x140. Four stages = full 16-lane tree sum.
template <int CTRL>
__device__ __forceinline__ float dpp_add(float x) {
  int t = __builtin_amdgcn_update_dpp(0, __float_as_int(x), CTRL, 0xf, 0xf, true);
  return x + __int_as_float(t);
}

// unpack u32-packed bf16 pairs into f32x2 pairs (feature 2p = lo, 2p+1 = hi)
__device__ __forceinline__ void unpk2(uint4 v, f32x2* o) {
  o[0] = (f32x2){bfl(v.x), bfh(v.x)};
  o[1] = (f32x2){bfl(v.y), bfh(v.y)};
  o[2] = (f32x2){bfl(v.z), bfh(v.z)};
  o[3] = (f32x2){bfl(v.w), bfh(v.w)};
}

// ---------------- dtype probe + cnt/dmeta zeroing ----------------
__global__ void probe_zero_kernel(const u16* __restrict__ x, const int* __restrict__ ei,
                                  int* __restrict__ flags, int* __restrict__ cnt,
                                  int* __restrict__ dmeta, int n) {
  int g = blockIdx.x * 256 + threadIdx.x;
  if (g < n) cnt[g] = 0;
  if (g < 128) dmeta[g] = 0;  // dcnt[64] + dticket[64]
  if (blockIdx.x == 0) {
    __shared__ int s_f32, s_i32;
    if (threadIdx.x == 0) { s_f32 = 0; s_i32 = 0; }
    __syncthreads();
    int lf = 0, li = 0;
    for (int i = threadIdx.x; i < 1024; i += 256) {
      float v = bf1(x[i]);
      if (!(fabsf(v) < 1e8f)) lf = 1;
      if (ei[2 * i + 1] != 0) li = 1;
    }
    if (lf) s_f32 = 1;
    if (li) s_i32 = 1;
    __syncthreads();
    if (threadIdx.x == 0) {
      flags[0] = s_f32;
      flags[1] = s_i32 ? 0 : 1;
    }
  }
}

// ---------------- CSR build ----------------
__device__ __forceinline__ int edge_val(const int* __restrict__ w, long j, int i64) {
  return i64 ? w[2 * j] : w[j];
}

__global__ void count_kernel(const int* __restrict__ ei, const int* __restrict__ flags,
                             int* __restrict__ cnt, int E) {
  int e = blockIdx.x * blockDim.x + threadIdx.x;
  if (e >= E) return;
  int d = edge_val(ei, (long)E + e, flags[1]);
  if ((u32)d < (u32)NN) atomicAdd(&cnt[d], 1);
}

// local scan + degree histogram (64 buckets, descending: b = 63 - min(deg,63))
__global__ void scan_local(const int* __restrict__ cnt, int* __restrict__ excl,
                           int* __restrict__ bsum, int* __restrict__ dcnt, int n) {
  __shared__ int sd[256];
  __shared__ int h[64];
  int t = threadIdx.x;
  if (t < 64) h[t] = 0;
  int g = blockIdx.x * 256 + t;
  int v = (g < n) ? cnt[g] : 0;
  sd[t] = v;
  __syncthreads();
  for (int off = 1; off < 256; off <<= 1) {
    int x = (t >= off) ? sd[t - off] : 0;
    __syncthreads();
    sd[t] += x;
    __syncthreads();
  }
  int incl = sd[t];
  if (g < n) excl[g] = incl - v;
  if (t == 255) bsum[blockIdx.x] = incl;
  if (g < n) atomicAdd(&h[63 - min(v, 63)], 1);
  __syncthreads();
  if (t < 64 && h[t]) atomicAdd(&dcnt[t], h[t]);
}

// scan_add with inlined block-offset reduction (absorbs old scan_totals)
__global__ void scan_add(const int* __restrict__ excl, const int* __restrict__ bsum,
                         const int* __restrict__ cnt, int* __restrict__ rowptr,
                         int* __restrict__ fillp, int n, int nb) {
  __shared__ int sd[256];
  int t = threadIdx.x;
  sd[t] = (t < nb && t < (int)blockIdx.x) ? bsum[t] : 0;
  __syncthreads();
  for (int off = 128; off > 0; off >>= 1) {
    if (t < off) sd[t] += sd[t + off];
    __syncthreads();
  }
  int boff = sd[0];
  int g = blockIdx.x * 256 + t;
  if (g < n) {
    int e2 = excl[g] + boff;
    rowptr[g] = e2;
    fillp[g] = e2;
    if (g == n - 1) rowptr[n] = e2 + cnt[g];
  }
}

// degree-sorted permutation (counting-sort scatter): each block builds the
// 64-bucket prefix in LDS, then nodes take a per-bucket ticket.
__global__ void deg_scatter(const int* __restrict__ cnt, const int* __restrict__ dcnt,
                            int* __restrict__ dticket, int* __restrict__ perm, int n) {
  __shared__ int sv[64], base[64];
  int t = threadIdx.x;
  if (t < 64) sv[t] = dcnt[t];
  __syncthreads();
  if (t == 0) {
    int r = 0;
    for (int i = 0; i < 64; ++i) { base[i] = r; r += sv[i]; }
  }
  __syncthreads();
  int g = blockIdx.x * 256 + t;
  if (g < n) {
    int b = 63 - min(cnt[g], 63);
    int pos = base[b] + atomicAdd(&dticket[b], 1);
    perm[pos] = g;
  }
}

__global__ void fill_kernel(const int* __restrict__ ei, const int* __restrict__ flags,
                            int* __restrict__ fillp, int* __restrict__ col, int E) {
  int e = blockIdx.x * blockDim.x + threadIdx.x;
  if (e >= E) return;
  int i64 = flags[1];
  int s = edge_val(ei, (long)e, i64);
  int d = edge_val(ei, (long)E + e, i64);
  if ((u32)d >= (u32)NN) return;
  int p = atomicAdd(&fillp[d], 1);
  col[p] = ((u32)s < (u32)NN) ? s : 0;
}

// ---------------- weight pre-transpose: Wt[j][k] = W[k][j], output bf16 ----------------
__global__ void transpose_w(const void* W0, const void* W1, const void* W2,
                            const void* W3, const void* W4, const void* W5,
                            u16* T0, u16* T1, u16* T2, u16* T3, u16* T4, u16* T5,
                            const int* __restrict__ flags) {
  int y = blockIdx.y;
  int M = (y < 3) ? 128 : 256;
  int flat = blockIdx.x * 256 + threadIdx.x;
  if (flat >= M * 128) return;
  int j = flat >> 7;
  int k = flat & 127;
  const void* W = (y == 0) ? W0 : (y == 1) ? W1 : (y == 2) ? W2 : (y == 3) ? W3 : (y == 4) ? W4 : W5;
  u16* T = (y == 0) ? T0 : (y == 1) ? T1 : (y == 2) ? T2 : (y == 3) ? T3 : (y == 4) ? T4 : T5;
  u16 v;
  if (flags[0])
    v = f2bf(((const float*)W)[(size_t)k * M + j]);
  else
    v = ((const u16*)W)[(size_t)k * M + j];
  T[(size_t)j * 128 + k] = v;
}

// ---------------- MFMA GEMM, z-merged (R12 proven) ----------------
#define LSTR 136
template <int MZ>
__global__ __launch_bounds__(256) void gemm3_mz(
    const void* __restrict__ X,
    const u16* __restrict__ Wta, const u16* __restrict__ Wtb, const u16* __restrict__ Wtc,
    const void* __restrict__ bias,
    u16* __restrict__ Ya, u16* __restrict__ Yb, u16* __restrict__ Yc,
    const int* __restrict__ flags, int x_follows, int N) {
  constexpr int M = MZ * 128;
  __shared__ __align__(16) u16 Xs[64 * LSTR];
  __shared__ __align__(16) u16 Bs[128 * LSTR];
  const int K = 128;
  int t = threadIdx.x;
  int lane = t & 63;
  int w = t >> 6;
  int n0g = blockIdx.x * 64;
  int F32X = x_follows ? flags[0] : 0;
  const u16* Wt = (blockIdx.y == 0) ? Wta : ((blockIdx.y == 1) ? Wtb : Wtc);
  u16* Y = (blockIdx.y == 0) ? Ya : ((blockIdx.y == 1) ? Yb : Yc);

  if (!F32X) {
    const u16* Xg = (const u16*)X;
    for (int it = 0; it < 4; ++it) {
      int i = t + 256 * it;
      int r = i >> 4, c8 = (i & 15) * 8;
      int n = n0g + r;
      uint4 v = make_uint4(0, 0, 0, 0);
      if (n < N) v = *(const uint4*)(Xg + (size_t)n * K + c8);
      *(uint4*)(Xs + r * LSTR + c8) = v;
    }
  } else {
    const float* Xg = (const float*)X;
    for (int it = 0; it < 4; ++it) {
      int i = t + 256 * it;
      int r = i >> 4, c8 = (i & 15) * 8;
      int n = n0g + r;
      uint4 pk = make_uint4(0, 0, 0, 0);
      if (n < N) {
        float4 f0 = *(const float4*)(Xg + (size_t)n * K + c8);
        float4 f1 = *(const float4*)(Xg + (size_t)n * K + c8 + 4);
        pk.x = (u32)f2bf(f0.x) | ((u32)f2bf(f0.y) << 16);
        pk.y = (u32)f2bf(f0.z) | ((u32)f2bf(f0.w) << 16);
        pk.z = (u32)f2bf(f1.x) | ((u32)f2bf(f1.y) << 16);
        pk.w = (u32)f2bf(f1.z) | ((u32)f2bf(f1.w) << 16);
      }
      *(uint4*)(Xs + r * LSTR + c8) = pk;
    }
  }

  int m0 = (w >> 1) * 32;
  int n0 = (w & 1) * 64;
  int l15 = lane & 15;
  int q8 = (lane >> 4) * 8;
  int F32B = flags[0];

#pragma unroll
  for (int z = 0; z < MZ; ++z) {
    int c0 = z * 128;
    for (int it = 0; it < 8; ++it) {
      int i = t + 256 * it;
      int j = i >> 4, k8 = (i & 15) * 8;
      uint4 v = *(const uint4*)(Wt + (size_t)(c0 + j) * K + k8);
      *(uint4*)(Bs + j * LSTR + k8) = v;
    }
    __syncthreads();

    f32x4 acc[2][4];
#pragma unroll
    for (int i = 0; i < 2; ++i)
#pragma unroll
      for (int j = 0; j < 4; ++j) acc[i][j] = (f32x4){0.f, 0.f, 0.f, 0.f};

#pragma unroll
    for (int kc = 0; kc < 4; ++kc) {
      int ko = kc * 32 + q8;
      bf16x8 a[2], b[4];
#pragma unroll
      for (int i = 0; i < 2; ++i)
        a[i] = *(const bf16x8*)(Xs + (m0 + i * 16 + l15) * LSTR + ko);
#pragma unroll
      for (int j = 0; j < 4; ++j)
        b[j] = *(const bf16x8*)(Bs + (n0 + j * 16 + l15) * LSTR + ko);
#pragma unroll
      for (int i = 0; i < 2; ++i)
#pragma unroll
        for (int j = 0; j < 4; ++j)
          acc[i][j] = __builtin_amdgcn_mfma_f32_16x16x32_bf16(a[i], b[j], acc[i][j], 0, 0, 0);
    }
    __syncthreads();

    float bv[4] = {0.f, 0.f, 0.f, 0.f};
    if (blockIdx.y == 2) {
#pragma unroll
      for (int j = 0; j < 4; ++j) {
        int c = c0 + n0 + j * 16 + l15;
        bv[j] = F32B ? ((const float*)bias)[c] : bf1(((const u16*)bias)[c]);
      }
    }

    u16* Ct = Bs;
#pragma unroll
    for (int i = 0; i < 2; ++i)
#pragma unroll
      for (int j = 0; j < 4; ++j) {
        int colj = n0 + j * 16 + l15;
        int rbase = m0 + i * 16 + (lane >> 4) * 4;
#pragma unroll
        for (int r = 0; r < 4; ++r)
          Ct[(rbase + r) * LSTR + colj] = f2bf(acc[i][j][r] + bv[j]);
      }
    __syncthreads();

    for (int it = 0; it < 4; ++it) {
      int i = t + 256 * it;
      int r = i >> 4, c8 = (i & 15) * 8;
      int n = n0g + r;
      if (n < N) {
        uint4 v = *(const uint4*)(Ct + r * LSTR + c8);
        *(uint4*)(Y + (size_t)n * M + c0 + c8) = v;
      }
    }
    __syncthreads();
  }
}

// ---------------- GATv2 aggregation v10: v9 + degree-sorted perm ----------------
// GL = 16 (F=128) or 32 (F=256); HEPL = 8 (uint4 gathers). Each GL-lane group
// owns one node taken from perm[] (degree-descending) so wave siblings have
// near-equal degree -> wave time ~ own degree, not max of a random draw.
// Depth-2 row pipeline; 4-DPP dot reduce (+shfl16 for GL=32); pk-f32 math;
// LeakyReLU = 0.6h + 0.4|h|; branchless per-node online softmax.
template <int F, bool ELU, int GL>
__global__ __launch_bounds__(256) void gat_agg_kernel(
    const u16* __restrict__ xl, const u16* __restrict__ xr, const u16* __restrict__ res,
    const void* __restrict__ att, const int* __restrict__ rowptr, const int* __restrict__ col,
    const int* __restrict__ perm,
    void* __restrict__ out, const int* __restrict__ flags, int out_follows, int N) {
  constexpr int HEPL = F / GL;      // 8
  constexpr int HP = HEPL / 2;      // 4
  static_assert(HEPL == 8, "GL must be F/8");
  int tid = threadIdx.x;
  int gl = tid & (GL - 1);          // lane within group
  int gid = blockIdx.x * (256 / GL) + (tid / GL);
  if (gid >= N) return;
  int node = perm[gid];
  int F32 = flags[0];
  int OF32 = out_follows ? F32 : 0;
  int base = gl * HEPL;

  f32x2 xr2[HP], att6[HP], att4[HP], acc2[HP];
  {
    uint4 xp = *(const uint4*)(xr + (size_t)node * F + base);
    unpk2(xp, xr2);
  }
  if (F32) {
    const float* af = (const float*)att + base;
#pragma unroll
    for (int p = 0; p < HP; ++p) {
      f32x2 a = (f32x2){af[2 * p], af[2 * p + 1]};
      att6[p] = a * 0.6f;
      att4[p] = a * 0.4f;
    }
  } else {
    f32x2 a2[HP];
    uint4 ap = *(const uint4*)((const u16*)att + base);
    unpk2(ap, a2);
#pragma unroll
    for (int p = 0; p < HP; ++p) {
      att6[p] = a2[p] * 0.6f;
      att4[p] = a2[p] * 0.4f;
    }
  }
#pragma unroll
  for (int p = 0; p < HP; ++p) acc2[p] = bc2(0.f);

  float m = -1e30f, l = 0.f;
  int beg = rowptr[node], end = rowptr[node + 1];
  int deg = end - beg;

  if (deg > 0) {
    int nit = (deg + 1) >> 1;
    int dm1 = deg - 1;
    auto ldc = [&](int j) -> int { return col[beg + min(j, dm1)]; };
    auto gat = [&](int c) -> uint4 { return *(const uint4*)(xl + (size_t)c * F + base); };

    // depth-2 pipeline: rows for iters t and t+1 in flight; cols for t+2
    int c4 = ldc(4), c5 = ldc(5);
    uint4 va = gat(ldc(0)), vb = gat(ldc(1)), vc = gat(ldc(2)), vd = gat(ldc(3));

    for (int t = 0; t < nit; ++t) {
      uint4 x0v = va, x1v = vb;
      int act1 = (2 * t + 1) < deg;
      va = vc; vb = vd;
      if (t + 2 < nit) { vc = gat(c4); vd = gat(c5); }
      if (t + 3 < nit) { c4 = ldc(2 * t + 6); c5 = ldc(2 * t + 7); }

      f32x2 x0[HP], x1[HP];
      unpk2(x0v, x0);
      unpk2(x1v, x1);
      f32x2 s0 = bc2(0.f), s1 = bc2(0.f);
#pragma unroll
      for (int p = 0; p < HP; ++p) {
        f32x2 h0 = x0[p] + xr2[p];
        f32x2 h1 = x1[p] + xr2[p];
        f32x2 ha0 = pkabs(h0);
        f32x2 ha1 = pkabs(h1);
        s0 = pkfma(att6[p], h0, s0);
        s1 = pkfma(att6[p], h1, s1);
        s0 = pkfma(att4[p], ha0, s0);
        s1 = pkfma(att4[p], ha1, s1);
      }
      float d0 = s0.x + s0.y;
      float d1 = s1.x + s1.y;
      // GL-lane tree sum: 4 DPP stages (16-lane scope); +shfl16 for GL=32
      d0 = dpp_add<0xB1>(d0);  d1 = dpp_add<0xB1>(d1);
      d0 = dpp_add<0x4E>(d0);  d1 = dpp_add<0x4E>(d1);
      d0 = dpp_add<0x141>(d0); d1 = dpp_add<0x141>(d1);
      d0 = dpp_add<0x140>(d0); d1 = dpp_add<0x140>(d1);
      if constexpr (GL == 32) {
        d0 += __shfl_xor(d0, 16, 64);
        d1 += __shfl_xor(d1, 16, 64);
      }

      float p0 = d0;                      // edge 2t always active (t < nit)
      float p1 = act1 ? d1 : -1e30f;
      // branchless online softmax; first iter: scl = exp(-1e30 - finite) = 0
      float mn = fmaxf(m, fmaxf(p0, p1));
      float scl = __expf(m - mn);
      float w0 = __expf(p0 - mn);
      float w1 = __expf(p1 - mn);
      l = fmaf(l, scl, w0 + w1);
      f32x2 w0b = bc2(w0), w1b = bc2(w1), sclb = bc2(scl);
#pragma unroll
      for (int p = 0; p < HP; ++p)
        acc2[p] = pkfma(sclb, acc2[p], pkfma(w1b, x1[p], w0b * x0[p]));
      m = mn;
    }
  }

  // epilogue: each group writes its own node slice
  float inv = 1.f / (l + 1e-16f);
  uint4 rp = *(const uint4*)(res + (size_t)node * F + base);
  f32x2 rv[HP];
  unpk2(rp, rv);
  f32x2 ov[HP];
  f32x2 invb = bc2(inv);
#pragma unroll
  for (int p = 0; p < HP; ++p) {
    f32x2 o = pkfma(acc2[p], invb, rv[p]);
    if (ELU) {
      o.x = (o.x > 0.f) ? o.x : (__expf(o.x) - 1.f);
      o.y = (o.y > 0.f) ? o.y : (__expf(o.y) - 1.f);
    }
    ov[p] = o;
  }
  if (OF32) {
    float* of = (float*)out + (size_t)node * F + base;
    float4 f0 = {ov[0].x, ov[0].y, ov[1].x, ov[1].y};
    float4 f1 = {ov[2].x, ov[2].y, ov[3].x, ov[3].y};
    *(float4*)of = f0;
    *(float4*)(of + 4) = f1;
  } else {
    u16* o16 = (u16*)out;
    uint4 pk;
    pk.x = (u32)f2bf(ov[0].x) | ((u32)f2bf(ov[0].y) << 16);
    pk.y = (u32)f2bf(ov[1].x) | ((u32)f2bf(ov[1].y) << 16);
    pk.z = (u32)f2bf(ov[2].x) | ((u32)f2bf(ov[2].y) << 16);
    pk.w = (u32)f2bf(ov[3].x) | ((u32)f2bf(ov[3].y) << 16);
    *(uint4*)(o16 + (size_t)node * F + base) = pk;
  }
}

extern "C" void kernel_launch(void* const* d_in, const int* in_sizes, int n_in,
                              void* d_out, int out_size, void* d_ws, size_t ws_size,
                              hipStream_t stream) {
  const u16* x16 = (const u16*)d_in[0];
  const int* ei = (const int*)d_in[1];
  const int N = NN, E = NE;

  char* ws = (char*)d_ws;
  size_t off = 0;
  auto alloc = [&](size_t bytes) -> void* {
    void* p = (void*)(ws + off);
    off += (bytes + 255) & ~(size_t)255;
    return p;
  };
  int* flags = (int*)alloc(2 * 4);
  int* cnt = (int*)alloc((size_t)N * 4);
  int* rowptr = (int*)alloc((size_t)(N + 1) * 4);
  int* fillp = (int*)alloc((size_t)N * 4);
  int* colb = (int*)alloc((size_t)E * 4);
  int* excl = (int*)alloc((size_t)N * 4);
  int* bsum = (int*)alloc(256 * 4);
  int* dmeta = (int*)alloc(128 * 4);   // dcnt[64] + dticket[64]
  int* perm = (int*)alloc((size_t)N * 4);
  u16* Wt1a = (u16*)alloc((size_t)128 * 128 * 2);
  u16* Wt1b = (u16*)alloc((size_t)128 * 128 * 2);
  u16* Wt1c = (u16*)alloc((size_t)128 * 128 * 2);
  u16* Wt2a = (u16*)alloc((size_t)256 * 128 * 2);
  u16* Wt2b = (u16*)alloc((size_t)256 * 128 * 2);
  u16* Wt2c = (u16*)alloc((size_t)256 * 128 * 2);
  u16* buf1 = (u16*)alloc((size_t)N * 256 * 2);
  u16* buf2 = (u16*)alloc((size_t)N * 256 * 2);
  u16* buf3 = (u16*)alloc((size_t)N * 256 * 2);
  u16* h1 = (u16*)alloc((size_t)N * 128 * 2);
  (void)ws_size; (void)n_in; (void)in_sizes; (void)out_size;

  int nb = (N + 255) / 256;
  int* dcnt = dmeta;
  int* dticket = dmeta + 64;

  probe_zero_kernel<<<nb, 256, 0, stream>>>(x16, ei, flags, cnt, dmeta, N);
  count_kernel<<<(E + 255) / 256, 256, 0, stream>>>(ei, flags, cnt, E);
  scan_local<<<nb, 256, 0, stream>>>(cnt, excl, bsum, dcnt, N);
  scan_add<<<nb, 256, 0, stream>>>(excl, bsum, cnt, rowptr, fillp, N, nb);
  deg_scatter<<<nb, 256, 0, stream>>>(cnt, dcnt, dticket, perm, N);
  fill_kernel<<<(E + 255) / 256, 256, 0, stream>>>(ei, flags, fillp, colb, E);
  transpose_w<<<dim3(128, 6), 256, 0, stream>>>(
      d_in[2], d_in[3], d_in[5], d_in[7], d_in[8], d_in[10],
      Wt1a, Wt1b, Wt1c, Wt2a, Wt2b, Wt2c, flags);

  int gx = (N + 63) / 64;
  gemm3_mz<1><<<dim3(gx, 3), 256, 0, stream>>>(
      d_in[0], Wt1a, Wt1b, Wt1c, d_in[6], buf1, buf2, buf3, flags, 1, N);
  gat_agg_kernel<128, true, 16><<<(N + 15) / 16, 256, 0, stream>>>(
      buf1, buf2, buf3, d_in[4], rowptr, colb, perm, h1, flags, 0, N);
  gemm3_mz<2><<<dim3(gx, 3), 256, 0, stream>>>(
      h1, Wt2a, Wt2b, Wt2c, d_in[11], buf1, buf2, buf3, flags, 0, N);
  gat_agg_kernel<256, false, 32><<<(N + 7) / 8, 256, 0, stream>>>(
      buf1, buf2, buf3, d_in[9], rowptr, colb, perm, d_out, flags, 1, N);
}

// Round 14
// 325.211 us; speedup vs baseline: 1.4573x; 1.4573x over previous
//
#include <hip/hip_runtime.h>

typedef unsigned short u16;
typedef unsigned int u32;
typedef __attribute__((ext_vector_type(8))) short bf16x8;
typedef __attribute__((ext_vector_type(4))) float f32x4;
typedef __attribute__((ext_vector_type(2))) float f32x2;

#define NN 50000
#define NE 640000

// ---- bf16 helpers (bf16 -> f32 exact: shift<<16; f32 -> bf16 RNE) ----
__device__ __forceinline__ float bfl(u32 u) { return __uint_as_float(u << 16); }
__device__ __forceinline__ float bfh(u32 u) { return __uint_as_float(u & 0xffff0000u); }
__device__ __forceinline__ float bf1(u16 v) { return __uint_as_float(((u32)v) << 16); }
__device__ __forceinline__ u16 f2bf(float f) {
  u32 u = __float_as_uint(f);
  u32 r = (u + 0x7fffu + ((u >> 16) & 1u)) >> 16;
  return (u16)r;
}

__device__ __forceinline__ f32x2 bc2(float s) { return (f32x2){s, s}; }
__device__ __forceinline__ f32x2 pkfma(f32x2 a, f32x2 b, f32x2 c) {
  return __builtin_elementwise_fma(a, b, c);  // -> v_pk_fma_f32 on CDNA
}
__device__ __forceinline__ f32x2 pkabs(f32x2 a) {
  return __builtin_elementwise_abs(a);
}

// DPP-based partial butterfly add (VALU pipe). All row-scoped (<=16 lanes):
// xor1 = quad_perm 0xB1; xor2 = quad_perm 0x4E; i^7-in-8 = row_half_mirror
// 0x141; i^15-in-16 = row_mirror 0x140. Four stages = full 16-lane tree sum.
template <int CTRL>
__device__ __forceinline__ float dpp_add(float x) {
  int t = __builtin_amdgcn_update_dpp(0, __float_as_int(x), CTRL, 0xf, 0xf, true);
  return x + __int_as_float(t);
}

// unpack u32-packed bf16 pairs into f32x2 pairs (feature 2p = lo, 2p+1 = hi)
__device__ __forceinline__ void unpk2(uint4 v, f32x2* o) {
  o[0] = (f32x2){bfl(v.x), bfh(v.x)};
  o[1] = (f32x2){bfl(v.y), bfh(v.y)};
  o[2] = (f32x2){bfl(v.z), bfh(v.z)};
  o[3] = (f32x2){bfl(v.w), bfh(v.w)};
}

// ---------------- dtype probe + cnt/dmeta zeroing ----------------
__global__ void probe_zero_kernel(const u16* __restrict__ x, const int* __restrict__ ei,
                                  int* __restrict__ flags, int* __restrict__ cnt,
                                  int* __restrict__ dmeta, int n) {
  int g = blockIdx.x * 256 + threadIdx.x;
  if (g < n) cnt[g] = 0;
  if (g < 128) dmeta[g] = 0;  // dcnt[64] + dticket[64]
  if (blockIdx.x == 0) {
    __shared__ int s_f32, s_i32;
    if (threadIdx.x == 0) { s_f32 = 0; s_i32 = 0; }
    __syncthreads();
    int lf = 0, li = 0;
    for (int i = threadIdx.x; i < 1024; i += 256) {
      float v = bf1(x[i]);
      if (!(fabsf(v) < 1e8f)) lf = 1;
      if (ei[2 * i + 1] != 0) li = 1;
    }
    if (lf) s_f32 = 1;
    if (li) s_i32 = 1;
    __syncthreads();
    if (threadIdx.x == 0) {
      flags[0] = s_f32;
      flags[1] = s_i32 ? 0 : 1;
    }
  }
}

// ---------------- CSR build ----------------
__device__ __forceinline__ int edge_val(const int* __restrict__ w, long j, int i64) {
  return i64 ? w[2 * j] : w[j];
}

__global__ void count_kernel(const int* __restrict__ ei, const int* __restrict__ flags,
                             int* __restrict__ cnt, int E) {
  int e = blockIdx.x * blockDim.x + threadIdx.x;
  if (e >= E) return;
  int d = edge_val(ei, (long)E + e, flags[1]);
  if ((u32)d < (u32)NN) atomicAdd(&cnt[d], 1);
}

// local scan + degree histogram (64 buckets, descending: b = 63 - min(deg,63))
__global__ void scan_local(const int* __restrict__ cnt, int* __restrict__ excl,
                           int* __restrict__ bsum, int* __restrict__ dcnt, int n) {
  __shared__ int sd[256];
  __shared__ int h[64];
  int t = threadIdx.x;
  if (t < 64) h[t] = 0;
  int g = blockIdx.x * 256 + t;
  int v = (g < n) ? cnt[g] : 0;
  sd[t] = v;
  __syncthreads();
  for (int off = 1; off < 256; off <<= 1) {
    int x = (t >= off) ? sd[t - off] : 0;
    __syncthreads();
    sd[t] += x;
    __syncthreads();
  }
  int incl = sd[t];
  if (g < n) excl[g] = incl - v;
  if (t == 255) bsum[blockIdx.x] = incl;
  if (g < n) atomicAdd(&h[63 - min(v, 63)], 1);
  __syncthreads();
  if (t < 64 && h[t]) atomicAdd(&dcnt[t], h[t]);
}

// scan_add with inlined block-offset reduction (absorbs old scan_totals)
__global__ void scan_add(const int* __restrict__ excl, const int* __restrict__ bsum,
                         const int* __restrict__ cnt, int* __restrict__ rowptr,
                         int* __restrict__ fillp, int n, int nb) {
  __shared__ int sd[256];
  int t = threadIdx.x;
  sd[t] = (t < nb && t < (int)blockIdx.x) ? bsum[t] : 0;
  __syncthreads();
  for (int off = 128; off > 0; off >>= 1) {
    if (t < off) sd[t] += sd[t + off];
    __syncthreads();
  }
  int boff = sd[0];
  int g = blockIdx.x * 256 + t;
  if (g < n) {
    int e2 = excl[g] + boff;
    rowptr[g] = e2;
    fillp[g] = e2;
    if (g == n - 1) rowptr[n] = e2 + cnt[g];
  }
}

// degree-sorted permutation, two-level tickets (fixes R13's 154 us contention
// disaster: 50K global atomics on ~15 hot words). Each node takes a LOCAL
// rank via LDS atomics; ONE global atomicAdd per (block, nonempty bucket)
// claims the block's ticket range (<=64 global atomics/block, 196/address).
__global__ void deg_scatter(const int* __restrict__ cnt, const int* __restrict__ dcnt,
                            int* __restrict__ dticket, int* __restrict__ perm, int n) {
  __shared__ int lh[64];       // local histogram -> local rank
  __shared__ int btick[64];    // this block's base ticket per bucket
  __shared__ int base[64];     // global exclusive prefix of bucket sizes
  int t = threadIdx.x;
  if (t < 64) lh[t] = 0;
  __syncthreads();
  int g = blockIdx.x * 256 + t;
  int b = 0, lrank = 0;
  if (g < n) {
    b = 63 - min(cnt[g], 63);
    lrank = atomicAdd(&lh[b], 1);     // LDS atomic: rank within block
  }
  __syncthreads();
  if (t < 64) {
    btick[t] = lh[t] ? atomicAdd(&dticket[t], lh[t]) : 0;  // 1 global atomic/bucket
    lh[t] = dcnt[t];                  // reuse lh as bucket-size staging
  }
  __syncthreads();
  if (t == 0) {
    int r = 0;
    for (int i = 0; i < 64; ++i) { base[i] = r; r += lh[i]; }
  }
  __syncthreads();
  if (g < n) perm[base[b] + btick[b] + lrank] = g;
}

__global__ void fill_kernel(const int* __restrict__ ei, const int* __restrict__ flags,
                            int* __restrict__ fillp, int* __restrict__ col, int E) {
  int e = blockIdx.x * blockDim.x + threadIdx.x;
  if (e >= E) return;
  int i64 = flags[1];
  int s = edge_val(ei, (long)e, i64);
  int d = edge_val(ei, (long)E + e, i64);
  if ((u32)d >= (u32)NN) return;
  int p = atomicAdd(&fillp[d], 1);
  col[p] = ((u32)s < (u32)NN) ? s : 0;
}

// ---------------- weight pre-transpose: Wt[j][k] = W[k][j], output bf16 ----------------
__global__ void transpose_w(const void* W0, const void* W1, const void* W2,
                            const void* W3, const void* W4, const void* W5,
                            u16* T0, u16* T1, u16* T2, u16* T3, u16* T4, u16* T5,
                            const int* __restrict__ flags) {
  int y = blockIdx.y;
  int M = (y < 3) ? 128 : 256;
  int flat = blockIdx.x * 256 + threadIdx.x;
  if (flat >= M * 128) return;
  int j = flat >> 7;
  int k = flat & 127;
  const void* W = (y == 0) ? W0 : (y == 1) ? W1 : (y == 2) ? W2 : (y == 3) ? W3 : (y == 4) ? W4 : W5;
  u16* T = (y == 0) ? T0 : (y == 1) ? T1 : (y == 2) ? T2 : (y == 3) ? T3 : (y == 4) ? T4 : T5;
  u16 v;
  if (flags[0])
    v = f2bf(((const float*)W)[(size_t)k * M + j]);
  else
    v = ((const u16*)W)[(size_t)k * M + j];
  T[(size_t)j * 128 + k] = v;
}

// ---------------- MFMA GEMM, z-merged (R12 proven) ----------------
#define LSTR 136
template <int MZ>
__global__ __launch_bounds__(256) void gemm3_mz(
    const void* __restrict__ X,
    const u16* __restrict__ Wta, const u16* __restrict__ Wtb, const u16* __restrict__ Wtc,
    const void* __restrict__ bias,
    u16* __restrict__ Ya, u16* __restrict__ Yb, u16* __restrict__ Yc,
    const int* __restrict__ flags, int x_follows, int N) {
  constexpr int M = MZ * 128;
  __shared__ __align__(16) u16 Xs[64 * LSTR];
  __shared__ __align__(16) u16 Bs[128 * LSTR];
  const int K = 128;
  int t = threadIdx.x;
  int lane = t & 63;
  int w = t >> 6;
  int n0g = blockIdx.x * 64;
  int F32X = x_follows ? flags[0] : 0;
  const u16* Wt = (blockIdx.y == 0) ? Wta : ((blockIdx.y == 1) ? Wtb : Wtc);
  u16* Y = (blockIdx.y == 0) ? Ya : ((blockIdx.y == 1) ? Yb : Yc);

  if (!F32X) {
    const u16* Xg = (const u16*)X;
    for (int it = 0; it < 4; ++it) {
      int i = t + 256 * it;
      int r = i >> 4, c8 = (i & 15) * 8;
      int n = n0g + r;
      uint4 v = make_uint4(0, 0, 0, 0);
      if (n < N) v = *(const uint4*)(Xg + (size_t)n * K + c8);
      *(uint4*)(Xs + r * LSTR + c8) = v;
    }
  } else {
    const float* Xg = (const float*)X;
    for (int it = 0; it < 4; ++it) {
      int i = t + 256 * it;
      int r = i >> 4, c8 = (i & 15) * 8;
      int n = n0g + r;
      uint4 pk = make_uint4(0, 0, 0, 0);
      if (n < N) {
        float4 f0 = *(const float4*)(Xg + (size_t)n * K + c8);
        float4 f1 = *(const float4*)(Xg + (size_t)n * K + c8 + 4);
        pk.x = (u32)f2bf(f0.x) | ((u32)f2bf(f0.y) << 16);
        pk.y = (u32)f2bf(f0.z) | ((u32)f2bf(f0.w) << 16);
        pk.z = (u32)f2bf(f1.x) | ((u32)f2bf(f1.y) << 16);
        pk.w = (u32)f2bf(f1.z) | ((u32)f2bf(f1.w) << 16);
      }
      *(uint4*)(Xs + r * LSTR + c8) = pk;
    }
  }

  int m0 = (w >> 1) * 32;
  int n0 = (w & 1) * 64;
  int l15 = lane & 15;
  int q8 = (lane >> 4) * 8;
  int F32B = flags[0];

#pragma unroll
  for (int z = 0; z < MZ; ++z) {
    int c0 = z * 128;
    for (int it = 0; it < 8; ++it) {
      int i = t + 256 * it;
      int j = i >> 4, k8 = (i & 15) * 8;
      uint4 v = *(const uint4*)(Wt + (size_t)(c0 + j) * K + k8);
      *(uint4*)(Bs + j * LSTR + k8) = v;
    }
    __syncthreads();

    f32x4 acc[2][4];
#pragma unroll
    for (int i = 0; i < 2; ++i)
#pragma unroll
      for (int j = 0; j < 4; ++j) acc[i][j] = (f32x4){0.f, 0.f, 0.f, 0.f};

#pragma unroll
    for (int kc = 0; kc < 4; ++kc) {
      int ko = kc * 32 + q8;
      bf16x8 a[2], b[4];
#pragma unroll
      for (int i = 0; i < 2; ++i)
        a[i] = *(const bf16x8*)(Xs + (m0 + i * 16 + l15) * LSTR + ko);
#pragma unroll
      for (int j = 0; j < 4; ++j)
        b[j] = *(const bf16x8*)(Bs + (n0 + j * 16 + l15) * LSTR + ko);
#pragma unroll
      for (int i = 0; i < 2; ++i)
#pragma unroll
        for (int j = 0; j < 4; ++j)
          acc[i][j] = __builtin_amdgcn_mfma_f32_16x16x32_bf16(a[i], b[j], acc[i][j], 0, 0, 0);
    }
    __syncthreads();

    float bv[4] = {0.f, 0.f, 0.f, 0.f};
    if (blockIdx.y == 2) {
#pragma unroll
      for (int j = 0; j < 4; ++j) {
        int c = c0 + n0 + j * 16 + l15;
        bv[j] = F32B ? ((const float*)bias)[c] : bf1(((const u16*)bias)[c]);
      }
    }

    u16* Ct = Bs;
#pragma unroll
    for (int i = 0; i < 2; ++i)
#pragma unroll
      for (int j = 0; j < 4; ++j) {
        int colj = n0 + j * 16 + l15;
        int rbase = m0 + i * 16 + (lane >> 4) * 4;
#pragma unroll
        for (int r = 0; r < 4; ++r)
          Ct[(rbase + r) * LSTR + colj] = f2bf(acc[i][j][r] + bv[j]);
      }
    __syncthreads();

    for (int it = 0; it < 4; ++it) {
      int i = t + 256 * it;
      int r = i >> 4, c8 = (i & 15) * 8;
      int n = n0g + r;
      if (n < N) {
        uint4 v = *(const uint4*)(Ct + r * LSTR + c8);
        *(uint4*)(Y + (size_t)n * M + c0 + c8) = v;
      }
    }
    __syncthreads();
  }
}

// ---------------- GATv2 aggregation v10: v9 + degree-sorted perm ----------------
// GL = 16 (F=128) or 32 (F=256); HEPL = 8 (uint4 gathers). Each GL-lane group
// owns one node taken from perm[] (degree-descending) so wave siblings have
// near-equal degree -> wave time ~ own degree, not max of a random draw.
// Depth-2 row pipeline; 4-DPP dot reduce (+shfl16 for GL=32); pk-f32 math;
// LeakyReLU = 0.6h + 0.4|h|; branchless per-node online softmax.
template <int F, bool ELU, int GL>
__global__ __launch_bounds__(256) void gat_agg_kernel(
    const u16* __restrict__ xl, const u16* __restrict__ xr, const u16* __restrict__ res,
    const void* __restrict__ att, const int* __restrict__ rowptr, const int* __restrict__ col,
    const int* __restrict__ perm,
    void* __restrict__ out, const int* __restrict__ flags, int out_follows, int N) {
  constexpr int HEPL = F / GL;      // 8
  constexpr int HP = HEPL / 2;      // 4
  static_assert(HEPL == 8, "GL must be F/8");
  int tid = threadIdx.x;
  int gl = tid & (GL - 1);          // lane within group
  int gid = blockIdx.x * (256 / GL) + (tid / GL);
  if (gid >= N) return;
  int node = perm[gid];
  int F32 = flags[0];
  int OF32 = out_follows ? F32 : 0;
  int base = gl * HEPL;

  f32x2 xr2[HP], att6[HP], att4[HP], acc2[HP];
  {
    uint4 xp = *(const uint4*)(xr + (size_t)node * F + base);
    unpk2(xp, xr2);
  }
  if (F32) {
    const float* af = (const float*)att + base;
#pragma unroll
    for (int p = 0; p < HP; ++p) {
      f32x2 a = (f32x2){af[2 * p], af[2 * p + 1]};
      att6[p] = a * 0.6f;
      att4[p] = a * 0.4f;
    }
  } else {
    f32x2 a2[HP];
    uint4 ap = *(const uint4*)((const u16*)att + base);
    unpk2(ap, a2);
#pragma unroll
    for (int p = 0; p < HP; ++p) {
      att6[p] = a2[p] * 0.6f;
      att4[p] = a2[p] * 0.4f;
    }
  }
#pragma unroll
  for (int p = 0; p < HP; ++p) acc2[p] = bc2(0.f);

  float m = -1e30f, l = 0.f;
  int beg = rowptr[node], end = rowptr[node + 1];
  int deg = end - beg;

  if (deg > 0) {
    int nit = (deg + 1) >> 1;
    int dm1 = deg - 1;
    auto ldc = [&](int j) -> int { return col[beg + min(j, dm1)]; };
    auto gat = [&](int c) -> uint4 { return *(const uint4*)(xl + (size_t)c * F + base); };

    // depth-2 pipeline: rows for iters t and t+1 in flight; cols for t+2
    int c4 = ldc(4), c5 = ldc(5);
    uint4 va = gat(ldc(0)), vb = gat(ldc(1)), vc = gat(ldc(2)), vd = gat(ldc(3));

    for (int t = 0; t < nit; ++t) {
      uint4 x0v = va, x1v = vb;
      int act1 = (2 * t + 1) < deg;
      va = vc; vb = vd;
      if (t + 2 < nit) { vc = gat(c4); vd = gat(c5); }
      if (t + 3 < nit) { c4 = ldc(2 * t + 6); c5 = ldc(2 * t + 7); }

      f32x2 x0[HP], x1[HP];
      unpk2(x0v, x0);
      unpk2(x1v, x1);
      f32x2 s0 = bc2(0.f), s1 = bc2(0.f);
#pragma unroll
      for (int p = 0; p < HP; ++p) {
        f32x2 h0 = x0[p] + xr2[p];
        f32x2 h1 = x1[p] + xr2[p];
        f32x2 ha0 = pkabs(h0);
        f32x2 ha1 = pkabs(h1);
        s0 = pkfma(att6[p], h0, s0);
        s1 = pkfma(att6[p], h1, s1);
        s0 = pkfma(att4[p], ha0, s0);
        s1 = pkfma(att4[p], ha1, s1);
      }
      float d0 = s0.x + s0.y;
      float d1 = s1.x + s1.y;
      // GL-lane tree sum: 4 DPP stages (16-lane scope); +shfl16 for GL=32
      d0 = dpp_add<0xB1>(d0);  d1 = dpp_add<0xB1>(d1);
      d0 = dpp_add<0x4E>(d0);  d1 = dpp_add<0x4E>(d1);
      d0 = dpp_add<0x141>(d0); d1 = dpp_add<0x141>(d1);
      d0 = dpp_add<0x140>(d0); d1 = dpp_add<0x140>(d1);
      if constexpr (GL == 32) {
        d0 += __shfl_xor(d0, 16, 64);
        d1 += __shfl_xor(d1, 16, 64);
      }

      float p0 = d0;                      // edge 2t always active (t < nit)
      float p1 = act1 ? d1 : -1e30f;
      // branchless online softmax; first iter: scl = exp(-1e30 - finite) = 0
      float mn = fmaxf(m, fmaxf(p0, p1));
      float scl = __expf(m - mn);
      float w0 = __expf(p0 - mn);
      float w1 = __expf(p1 - mn);
      l = fmaf(l, scl, w0 + w1);
      f32x2 w0b = bc2(w0), w1b = bc2(w1), sclb = bc2(scl);
#pragma unroll
      for (int p = 0; p < HP; ++p)
        acc2[p] = pkfma(sclb, acc2[p], pkfma(w1b, x1[p], w0b * x0[p]));
      m = mn;
    }
  }

  // epilogue: each group writes its own node slice
  float inv = 1.f / (l + 1e-16f);
  uint4 rp = *(const uint4*)(res + (size_t)node * F + base);
  f32x2 rv[HP];
  unpk2(rp, rv);
  f32x2 ov[HP];
  f32x2 invb = bc2(inv);
#pragma unroll
  for (int p = 0; p < HP; ++p) {
    f32x2 o = pkfma(acc2[p], invb, rv[p]);
    if (ELU) {
      o.x = (o.x > 0.f) ? o.x : (__expf(o.x) - 1.f);
      o.y = (o.y > 0.f) ? o.y : (__expf(o.y) - 1.f);
    }
    ov[p] = o;
  }
  if (OF32) {
    float* of = (float*)out + (size_t)node * F + base;
    float4 f0 = {ov[0].x, ov[0].y, ov[1].x, ov[1].y};
    float4 f1 = {ov[2].x, ov[2].y, ov[3].x, ov[3].y};
    *(float4*)of = f0;
    *(float4*)(of + 4) = f1;
  } else {
    u16* o16 = (u16*)out;
    uint4 pk;
    pk.x = (u32)f2bf(ov[0].x) | ((u32)f2bf(ov[0].y) << 16);
    pk.y = (u32)f2bf(ov[1].x) | ((u32)f2bf(ov[1].y) << 16);
    pk.z = (u32)f2bf(ov[2].x) | ((u32)f2bf(ov[2].y) << 16);
    pk.w = (u32)f2bf(ov[3].x) | ((u32)f2bf(ov[3].y) << 16);
    *(uint4*)(o16 + (size_t)node * F + base) = pk;
  }
}

extern "C" void kernel_launch(void* const* d_in, const int* in_sizes, int n_in,
                              void* d_out, int out_size, void* d_ws, size_t ws_size,
                              hipStream_t stream) {
  const u16* x16 = (const u16*)d_in[0];
  const int* ei = (const int*)d_in[1];
  const int N = NN, E = NE;

  char* ws = (char*)d_ws;
  size_t off = 0;
  auto alloc = [&](size_t bytes) -> void* {
    void* p = (void*)(ws + off);
    off += (bytes + 255) & ~(size_t)255;
    return p;
  };
  int* flags = (int*)alloc(2 * 4);
  int* cnt = (int*)alloc((size_t)N * 4);
  int* rowptr = (int*)alloc((size_t)(N + 1) * 4);
  int* fillp = (int*)alloc((size_t)N * 4);
  int* colb = (int*)alloc((size_t)E * 4);
  int* excl = (int*)alloc((size_t)N * 4);
  int* bsum = (int*)alloc(256 * 4);
  int* dmeta = (int*)alloc(128 * 4);   // dcnt[64] + dticket[64]
  int* perm = (int*)alloc((size_t)N * 4);
  u16* Wt1a = (u16*)alloc((size_t)128 * 128 * 2);
  u16* Wt1b = (u16*)alloc((size_t)128 * 128 * 2);
  u16* Wt1c = (u16*)alloc((size_t)128 * 128 * 2);
  u16* Wt2a = (u16*)alloc((size_t)256 * 128 * 2);
  u16* Wt2b = (u16*)alloc((size_t)256 * 128 * 2);
  u16* Wt2c = (u16*)alloc((size_t)256 * 128 * 2);
  u16* buf1 = (u16*)alloc((size_t)N * 256 * 2);
  u16* buf2 = (u16*)alloc((size_t)N * 256 * 2);
  u16* buf3 = (u16*)alloc((size_t)N * 256 * 2);
  u16* h1 = (u16*)alloc((size_t)N * 128 * 2);
  (void)ws_size; (void)n_in; (void)in_sizes; (void)out_size;

  int nb = (N + 255) / 256;
  int* dcnt = dmeta;
  int* dticket = dmeta + 64;

  probe_zero_kernel<<<nb, 256, 0, stream>>>(x16, ei, flags, cnt, dmeta, N);
  count_kernel<<<(E + 255) / 256, 256, 0, stream>>>(ei, flags, cnt, E);
  scan_local<<<nb, 256, 0, stream>>>(cnt, excl, bsum, dcnt, N);
  scan_add<<<nb, 256, 0, stream>>>(excl, bsum, cnt, rowptr, fillp, N, nb);
  deg_scatter<<<nb, 256, 0, stream>>>(cnt, dcnt, dticket, perm, N);
  fill_kernel<<<(E + 255) / 256, 256, 0, stream>>>(ei, flags, fillp, colb, E);
  transpose_w<<<dim3(128, 6), 256, 0, stream>>>(
      d_in[2], d_in[3], d_in[5], d_in[7], d_in[8], d_in[10],
      Wt1a, Wt1b, Wt1c, Wt2a, Wt2b, Wt2c, flags);

  int gx = (N + 63) / 64;
  gemm3_mz<1><<<dim3(gx, 3), 256, 0, stream>>>(
      d_in[0], Wt1a, Wt1b, Wt1c, d_in[6], buf1, buf2, buf3, flags, 1, N);
  gat_agg_kernel<128, true, 16><<<(N + 15) / 16, 256, 0, stream>>>(
      buf1, buf2, buf3, d_in[4], rowptr, colb, perm, h1, flags, 0, N);
  gemm3_mz<2><<<dim3(gx, 3), 256, 0, stream>>>(
      h1, Wt2a, Wt2b, Wt2c, d_in[11], buf1, buf2, buf3, flags, 0, N);
  gat_agg_kernel<256, false, 32><<<(N + 7) / 8, 256, 0, stream>>>(
      buf1, buf2, buf3, d_in[9], rowptr, colb, perm, d_out, flags, 1, N);
}

// Round 15
// 314.675 us; speedup vs baseline: 1.5061x; 1.0335x over previous
//
#include <hip/hip_runtime.h>

typedef unsigned short u16;
typedef unsigned int u32;
typedef __attribute__((ext_vector_type(8))) short bf16x8;
typedef __attribute__((ext_vector_type(4))) float f32x4;
typedef __attribute__((ext_vector_type(2))) float f32x2;

#define NN 50000
#define NE 640000

// ---- bf16 helpers (bf16 -> f32 exact: shift<<16; f32 -> bf16 RNE) ----
__device__ __forceinline__ float bfl(u32 u) { return __uint_as_float(u << 16); }
__device__ __forceinline__ float bfh(u32 u) { return __uint_as_float(u & 0xffff0000u); }
__device__ __forceinline__ float bf1(u16 v) { return __uint_as_float(((u32)v) << 16); }
__device__ __forceinline__ u16 f2bf(float f) {
  u32 u = __float_as_uint(f);
  u32 r = (u + 0x7fffu + ((u >> 16) & 1u)) >> 16;
  return (u16)r;
}

__device__ __forceinline__ f32x2 bc2(float s) { return (f32x2){s, s}; }
__device__ __forceinline__ f32x2 pkfma(f32x2 a, f32x2 b, f32x2 c) {
  return __builtin_elementwise_fma(a, b, c);  // -> v_pk_fma_f32 on CDNA
}
__device__ __forceinline__ f32x2 pkabs(f32x2 a) {
  return __builtin_elementwise_abs(a);
}

// DPP-based partial butterfly add (VALU pipe). All row-scoped (<=16 lanes):
// xor1 = quad_perm 0xB1; xor2 = quad_perm 0x4E; i^7-in-8 = row_half_mirror
// 0x141; i^15-in-16 = row_mirror 0x140. Four stages = full 16-lane tree sum.
template <int CTRL>
__device__ __forceinline__ float dpp_add(float x) {
  int t = __builtin_amdgcn_update_dpp(0, __float_as_int(x), CTRL, 0xf, 0xf, true);
  return x + __int_as_float(t);
}

// unpack u32-packed bf16 pairs into f32x2 pairs (feature 2p = lo, 2p+1 = hi)
__device__ __forceinline__ void unpk2(uint4 v, f32x2* o) {
  o[0] = (f32x2){bfl(v.x), bfh(v.x)};
  o[1] = (f32x2){bfl(v.y), bfh(v.y)};
  o[2] = (f32x2){bfl(v.z), bfh(v.z)};
  o[3] = (f32x2){bfl(v.w), bfh(v.w)};
}

// ---------------- dtype probe + cnt/dmeta zeroing ----------------
__global__ void probe_zero_kernel(const u16* __restrict__ x, const int* __restrict__ ei,
                                  int* __restrict__ flags, int* __restrict__ cnt,
                                  int* __restrict__ dmeta, int n) {
  int g = blockIdx.x * 256 + threadIdx.x;
  if (g < n) cnt[g] = 0;
  if (g < 128) dmeta[g] = 0;  // dcnt[64] + dticket[64]
  if (blockIdx.x == 0) {
    __shared__ int s_f32, s_i32;
    if (threadIdx.x == 0) { s_f32 = 0; s_i32 = 0; }
    __syncthreads();
    int lf = 0, li = 0;
    for (int i = threadIdx.x; i < 1024; i += 256) {
      float v = bf1(x[i]);
      if (!(fabsf(v) < 1e8f)) lf = 1;
      if (ei[2 * i + 1] != 0) li = 1;
    }
    if (lf) s_f32 = 1;
    if (li) s_i32 = 1;
    __syncthreads();
    if (threadIdx.x == 0) {
      flags[0] = s_f32;
      flags[1] = s_i32 ? 0 : 1;
    }
  }
}

// ---------------- CSR build ----------------
__device__ __forceinline__ int edge_val(const int* __restrict__ w, long j, int i64) {
  return i64 ? w[2 * j] : w[j];
}

__global__ void count_kernel(const int* __restrict__ ei, const int* __restrict__ flags,
                             int* __restrict__ cnt, int E) {
  int e = blockIdx.x * blockDim.x + threadIdx.x;
  if (e >= E) return;
  int d = edge_val(ei, (long)E + e, flags[1]);
  if ((u32)d < (u32)NN) atomicAdd(&cnt[d], 1);
}

// local scan + degree histogram (64 buckets, descending: b = 63 - min(deg,63))
__global__ void scan_local(const int* __restrict__ cnt, int* __restrict__ excl,
                           int* __restrict__ bsum, int* __restrict__ dcnt, int n) {
  __shared__ int sd[256];
  __shared__ int h[64];
  int t = threadIdx.x;
  if (t < 64) h[t] = 0;
  int g = blockIdx.x * 256 + t;
  int v = (g < n) ? cnt[g] : 0;
  sd[t] = v;
  __syncthreads();
  for (int off = 1; off < 256; off <<= 1) {
    int x = (t >= off) ? sd[t - off] : 0;
    __syncthreads();
    sd[t] += x;
    __syncthreads();
  }
  int incl = sd[t];
  if (g < n) excl[g] = incl - v;
  if (t == 255) bsum[blockIdx.x] = incl;
  if (g < n) atomicAdd(&h[63 - min(v, 63)], 1);
  __syncthreads();
  if (t < 64 && h[t]) atomicAdd(&dcnt[t], h[t]);
}

// scan_add with inlined block-offset reduction (absorbs old scan_totals)
__global__ void scan_add(const int* __restrict__ excl, const int* __restrict__ bsum,
                         const int* __restrict__ cnt, int* __restrict__ rowptr,
                         int* __restrict__ fillp, int n, int nb) {
  __shared__ int sd[256];
  int t = threadIdx.x;
  sd[t] = (t < nb && t < (int)blockIdx.x) ? bsum[t] : 0;
  __syncthreads();
  for (int off = 128; off > 0; off >>= 1) {
    if (t < off) sd[t] += sd[t + off];
    __syncthreads();
  }
  int boff = sd[0];
  int g = blockIdx.x * 256 + t;
  if (g < n) {
    int e2 = excl[g] + boff;
    rowptr[g] = e2;
    fillp[g] = e2;
    if (g == n - 1) rowptr[n] = e2 + cnt[g];
  }
}

// degree-sorted permutation, two-level tickets (R14 proven: LDS local rank +
// one global atomic per (block, nonempty bucket)). Now writes a PACKED
// descriptor {node, beg, end, 0} so the agg prologue's dependent-load chain
// shrinks from 4 deep (perm -> rowptr x2 -> col -> gather) to 3 deep.
__global__ void deg_scatter(const int* __restrict__ cnt, const int* __restrict__ rowptr,
                            const int* __restrict__ dcnt,
                            int* __restrict__ dticket, uint4* __restrict__ perm4, int n) {
  __shared__ int lh[64];       // local histogram -> local rank
  __shared__ int btick[64];    // this block's base ticket per bucket
  __shared__ int base[64];     // global exclusive prefix of bucket sizes
  int t = threadIdx.x;
  if (t < 64) lh[t] = 0;
  __syncthreads();
  int g = blockIdx.x * 256 + t;
  int b = 0, lrank = 0, dg = 0;
  if (g < n) {
    dg = cnt[g];
    b = 63 - min(dg, 63);
    lrank = atomicAdd(&lh[b], 1);     // LDS atomic: rank within block
  }
  __syncthreads();
  if (t < 64) {
    btick[t] = lh[t] ? atomicAdd(&dticket[t], lh[t]) : 0;  // 1 global atomic/bucket
    lh[t] = dcnt[t];                  // reuse lh as bucket-size staging
  }
  __syncthreads();
  if (t == 0) {
    int r = 0;
    for (int i = 0; i < 64; ++i) { base[i] = r; r += lh[i]; }
  }
  __syncthreads();
  if (g < n) {
    int rp = rowptr[g];
    perm4[base[b] + btick[b] + lrank] = make_uint4((u32)g, (u32)rp, (u32)(rp + dg), 0u);
  }
}

__global__ void fill_kernel(const int* __restrict__ ei, const int* __restrict__ flags,
                            int* __restrict__ fillp, int* __restrict__ col, int E) {
  int e = blockIdx.x * blockDim.x + threadIdx.x;
  if (e >= E) return;
  int i64 = flags[1];
  int s = edge_val(ei, (long)e, i64);
  int d = edge_val(ei, (long)E + e, i64);
  if ((u32)d >= (u32)NN) return;
  int p = atomicAdd(&fillp[d], 1);
  col[p] = ((u32)s < (u32)NN) ? s : 0;
}

// ---------------- weight pre-transpose: Wt[j][k] = W[k][j], output bf16 ----------------
__global__ void transpose_w(const void* W0, const void* W1, const void* W2,
                            const void* W3, const void* W4, const void* W5,
                            u16* T0, u16* T1, u16* T2, u16* T3, u16* T4, u16* T5,
                            const int* __restrict__ flags) {
  int y = blockIdx.y;
  int M = (y < 3) ? 128 : 256;
  int flat = blockIdx.x * 256 + threadIdx.x;
  if (flat >= M * 128) return;
  int j = flat >> 7;
  int k = flat & 127;
  const void* W = (y == 0) ? W0 : (y == 1) ? W1 : (y == 2) ? W2 : (y == 3) ? W3 : (y == 4) ? W4 : W5;
  u16* T = (y == 0) ? T0 : (y == 1) ? T1 : (y == 2) ? T2 : (y == 3) ? T3 : (y == 4) ? T4 : T5;
  u16 v;
  if (flags[0])
    v = f2bf(((const float*)W)[(size_t)k * M + j]);
  else
    v = ((const u16*)W)[(size_t)k * M + j];
  T[(size_t)j * 128 + k] = v;
}

// ---------------- MFMA GEMM, z-merged (R12 proven) ----------------
#define LSTR 136
template <int MZ>
__global__ __launch_bounds__(256) void gemm3_mz(
    const void* __restrict__ X,
    const u16* __restrict__ Wta, const u16* __restrict__ Wtb, const u16* __restrict__ Wtc,
    const void* __restrict__ bias,
    u16* __restrict__ Ya, u16* __restrict__ Yb, u16* __restrict__ Yc,
    const int* __restrict__ flags, int x_follows, int N) {
  constexpr int M = MZ * 128;
  __shared__ __align__(16) u16 Xs[64 * LSTR];
  __shared__ __align__(16) u16 Bs[128 * LSTR];
  const int K = 128;
  int t = threadIdx.x;
  int lane = t & 63;
  int w = t >> 6;
  int n0g = blockIdx.x * 64;
  int F32X = x_follows ? flags[0] : 0;
  const u16* Wt = (blockIdx.y == 0) ? Wta : ((blockIdx.y == 1) ? Wtb : Wtc);
  u16* Y = (blockIdx.y == 0) ? Ya : ((blockIdx.y == 1) ? Yb : Yc);

  if (!F32X) {
    const u16* Xg = (const u16*)X;
    for (int it = 0; it < 4; ++it) {
      int i = t + 256 * it;
      int r = i >> 4, c8 = (i & 15) * 8;
      int n = n0g + r;
      uint4 v = make_uint4(0, 0, 0, 0);
      if (n < N) v = *(const uint4*)(Xg + (size_t)n * K + c8);
      *(uint4*)(Xs + r * LSTR + c8) = v;
    }
  } else {
    const float* Xg = (const float*)X;
    for (int it = 0; it < 4; ++it) {
      int i = t + 256 * it;
      int r = i >> 4, c8 = (i & 15) * 8;
      int n = n0g + r;
      uint4 pk = make_uint4(0, 0, 0, 0);
      if (n < N) {
        float4 f0 = *(const float4*)(Xg + (size_t)n * K + c8);
        float4 f1 = *(const float4*)(Xg + (size_t)n * K + c8 + 4);
        pk.x = (u32)f2bf(f0.x) | ((u32)f2bf(f0.y) << 16);
        pk.y = (u32)f2bf(f0.z) | ((u32)f2bf(f0.w) << 16);
        pk.z = (u32)f2bf(f1.x) | ((u32)f2bf(f1.y) << 16);
        pk.w = (u32)f2bf(f1.z) | ((u32)f2bf(f1.w) << 16);
      }
      *(uint4*)(Xs + r * LSTR + c8) = pk;
    }
  }

  int m0 = (w >> 1) * 32;
  int n0 = (w & 1) * 64;
  int l15 = lane & 15;
  int q8 = (lane >> 4) * 8;
  int F32B = flags[0];

#pragma unroll
  for (int z = 0; z < MZ; ++z) {
    int c0 = z * 128;
    for (int it = 0; it < 8; ++it) {
      int i = t + 256 * it;
      int j = i >> 4, k8 = (i & 15) * 8;
      uint4 v = *(const uint4*)(Wt + (size_t)(c0 + j) * K + k8);
      *(uint4*)(Bs + j * LSTR + k8) = v;
    }
    __syncthreads();

    f32x4 acc[2][4];
#pragma unroll
    for (int i = 0; i < 2; ++i)
#pragma unroll
      for (int j = 0; j < 4; ++j) acc[i][j] = (f32x4){0.f, 0.f, 0.f, 0.f};

#pragma unroll
    for (int kc = 0; kc < 4; ++kc) {
      int ko = kc * 32 + q8;
      bf16x8 a[2], b[4];
#pragma unroll
      for (int i = 0; i < 2; ++i)
        a[i] = *(const bf16x8*)(Xs + (m0 + i * 16 + l15) * LSTR + ko);
#pragma unroll
      for (int j = 0; j < 4; ++j)
        b[j] = *(const bf16x8*)(Bs + (n0 + j * 16 + l15) * LSTR + ko);
#pragma unroll
      for (int i = 0; i < 2; ++i)
#pragma unroll
        for (int j = 0; j < 4; ++j)
          acc[i][j] = __builtin_amdgcn_mfma_f32_16x16x32_bf16(a[i], b[j], acc[i][j], 0, 0, 0);
    }
    __syncthreads();

    float bv[4] = {0.f, 0.f, 0.f, 0.f};
    if (blockIdx.y == 2) {
#pragma unroll
      for (int j = 0; j < 4; ++j) {
        int c = c0 + n0 + j * 16 + l15;
        bv[j] = F32B ? ((const float*)bias)[c] : bf1(((const u16*)bias)[c]);
      }
    }

    u16* Ct = Bs;
#pragma unroll
    for (int i = 0; i < 2; ++i)
#pragma unroll
      for (int j = 0; j < 4; ++j) {
        int colj = n0 + j * 16 + l15;
        int rbase = m0 + i * 16 + (lane >> 4) * 4;
#pragma unroll
        for (int r = 0; r < 4; ++r)
          Ct[(rbase + r) * LSTR + colj] = f2bf(acc[i][j][r] + bv[j]);
      }
    __syncthreads();

    for (int it = 0; it < 4; ++it) {
      int i = t + 256 * it;
      int r = i >> 4, c8 = (i & 15) * 8;
      int n = n0g + r;
      if (n < N) {
        uint4 v = *(const uint4*)(Ct + r * LSTR + c8);
        *(uint4*)(Y + (size_t)n * M + c0 + c8) = v;
      }
    }
    __syncthreads();
  }
}

// ---------------- GATv2 aggregation v11: packed perm4 + early res load ----------------
// GL = 16 (F=128) or 32 (F=256); HEPL = 8 (uint4 gathers). Each GL-lane group
// owns one node from perm4[] (degree-descending; {node,beg,end} packed so the
// prologue chain is perm4 -> col -> gather, 3 deep). res row loaded in the
// prologue (independent of loop) and consumed in the epilogue. Depth-2 row
// pipeline; 4-DPP dot reduce (+shfl16 for GL=32); pk-f32 math; LeakyReLU =
// 0.6h + 0.4|h|; branchless per-node online softmax.
template <int F, bool ELU, int GL>
__global__ __launch_bounds__(256) void gat_agg_kernel(
    const u16* __restrict__ xl, const u16* __restrict__ xr, const u16* __restrict__ res,
    const void* __restrict__ att, const uint4* __restrict__ perm4,
    const int* __restrict__ col,
    void* __restrict__ out, const int* __restrict__ flags, int out_follows, int N) {
  constexpr int HEPL = F / GL;      // 8
  constexpr int HP = HEPL / 2;      // 4
  static_assert(HEPL == 8, "GL must be F/8");
  int tid = threadIdx.x;
  int gl = tid & (GL - 1);          // lane within group
  int gid = blockIdx.x * (256 / GL) + (tid / GL);
  if (gid >= N) return;
  uint4 pk4 = perm4[gid];
  int node = (int)pk4.x;
  int beg = (int)pk4.y;
  int end = (int)pk4.z;
  int F32 = flags[0];
  int OF32 = out_follows ? F32 : 0;
  int base = gl * HEPL;

  f32x2 xr2[HP], att6[HP], att4[HP], acc2[HP];
  {
    uint4 xp = *(const uint4*)(xr + (size_t)node * F + base);
    unpk2(xp, xr2);
  }
  // early res load: independent of the loop, consumed in the epilogue
  uint4 rp4 = *(const uint4*)(res + (size_t)node * F + base);
  if (F32) {
    const float* af = (const float*)att + base;
#pragma unroll
    for (int p = 0; p < HP; ++p) {
      f32x2 a = (f32x2){af[2 * p], af[2 * p + 1]};
      att6[p] = a * 0.6f;
      att4[p] = a * 0.4f;
    }
  } else {
    f32x2 a2[HP];
    uint4 ap = *(const uint4*)((const u16*)att + base);
    unpk2(ap, a2);
#pragma unroll
    for (int p = 0; p < HP; ++p) {
      att6[p] = a2[p] * 0.6f;
      att4[p] = a2[p] * 0.4f;
    }
  }
#pragma unroll
  for (int p = 0; p < HP; ++p) acc2[p] = bc2(0.f);

  float m = -1e30f, l = 0.f;
  int deg = end - beg;

  if (deg > 0) {
    int nit = (deg + 1) >> 1;
    int dm1 = deg - 1;
    auto ldc = [&](int j) -> int { return col[beg + min(j, dm1)]; };
    auto gat = [&](int c) -> uint4 { return *(const uint4*)(xl + (size_t)c * F + base); };

    // depth-2 pipeline: rows for iters t and t+1 in flight; cols for t+2
    int c4 = ldc(4), c5 = ldc(5);
    uint4 va = gat(ldc(0)), vb = gat(ldc(1)), vc = gat(ldc(2)), vd = gat(ldc(3));

    for (int t = 0; t < nit; ++t) {
      uint4 x0v = va, x1v = vb;
      int act1 = (2 * t + 1) < deg;
      va = vc; vb = vd;
      if (t + 2 < nit) { vc = gat(c4); vd = gat(c5); }
      if (t + 3 < nit) { c4 = ldc(2 * t + 6); c5 = ldc(2 * t + 7); }

      f32x2 x0[HP], x1[HP];
      unpk2(x0v, x0);
      unpk2(x1v, x1);
      f32x2 s0 = bc2(0.f), s1 = bc2(0.f);
#pragma unroll
      for (int p = 0; p < HP; ++p) {
        f32x2 h0 = x0[p] + xr2[p];
        f32x2 h1 = x1[p] + xr2[p];
        f32x2 ha0 = pkabs(h0);
        f32x2 ha1 = pkabs(h1);
        s0 = pkfma(att6[p], h0, s0);
        s1 = pkfma(att6[p], h1, s1);
        s0 = pkfma(att4[p], ha0, s0);
        s1 = pkfma(att4[p], ha1, s1);
      }
      float d0 = s0.x + s0.y;
      float d1 = s1.x + s1.y;
      // GL-lane tree sum: 4 DPP stages (16-lane scope); +shfl16 for GL=32
      d0 = dpp_add<0xB1>(d0);  d1 = dpp_add<0xB1>(d1);
      d0 = dpp_add<0x4E>(d0);  d1 = dpp_add<0x4E>(d1);
      d0 = dpp_add<0x141>(d0); d1 = dpp_add<0x141>(d1);
      d0 = dpp_add<0x140>(d0); d1 = dpp_add<0x140>(d1);
      if constexpr (GL == 32) {
        d0 += __shfl_xor(d0, 16, 64);
        d1 += __shfl_xor(d1, 16, 64);
      }

      float p0 = d0;                      // edge 2t always active (t < nit)
      float p1 = act1 ? d1 : -1e30f;
      // branchless online softmax; first iter: scl = exp(-1e30 - finite) = 0
      float mn = fmaxf(m, fmaxf(p0, p1));
      float scl = __expf(m - mn);
      float w0 = __expf(p0 - mn);
      float w1 = __expf(p1 - mn);
      l = fmaf(l, scl, w0 + w1);
      f32x2 w0b = bc2(w0), w1b = bc2(w1), sclb = bc2(scl);
#pragma unroll
      for (int p = 0; p < HP; ++p)
        acc2[p] = pkfma(sclb, acc2[p], pkfma(w1b, x1[p], w0b * x0[p]));
      m = mn;
    }
  }

  // epilogue: each group writes its own node slice (res already in registers)
  float inv = 1.f / (l + 1e-16f);
  f32x2 rv[HP];
  unpk2(rp4, rv);
  f32x2 ov[HP];
  f32x2 invb = bc2(inv);
#pragma unroll
  for (int p = 0; p < HP; ++p) {
    f32x2 o = pkfma(acc2[p], invb, rv[p]);
    if (ELU) {
      o.x = (o.x > 0.f) ? o.x : (__expf(o.x) - 1.f);
      o.y = (o.y > 0.f) ? o.y : (__expf(o.y) - 1.f);
    }
    ov[p] = o;
  }
  if (OF32) {
    float* of = (float*)out + (size_t)node * F + base;
    float4 f0 = {ov[0].x, ov[0].y, ov[1].x, ov[1].y};
    float4 f1 = {ov[2].x, ov[2].y, ov[3].x, ov[3].y};
    *(float4*)of = f0;
    *(float4*)(of + 4) = f1;
  } else {
    u16* o16 = (u16*)out;
    uint4 pk;
    pk.x = (u32)f2bf(ov[0].x) | ((u32)f2bf(ov[0].y) << 16);
    pk.y = (u32)f2bf(ov[1].x) | ((u32)f2bf(ov[1].y) << 16);
    pk.z = (u32)f2bf(ov[2].x) | ((u32)f2bf(ov[2].y) << 16);
    pk.w = (u32)f2bf(ov[3].x) | ((u32)f2bf(ov[3].y) << 16);
    *(uint4*)(o16 + (size_t)node * F + base) = pk;
  }
}

extern "C" void kernel_launch(void* const* d_in, const int* in_sizes, int n_in,
                              void* d_out, int out_size, void* d_ws, size_t ws_size,
                              hipStream_t stream) {
  const u16* x16 = (const u16*)d_in[0];
  const int* ei = (const int*)d_in[1];
  const int N = NN, E = NE;

  char* ws = (char*)d_ws;
  size_t off = 0;
  auto alloc = [&](size_t bytes) -> void* {
    void* p = (void*)(ws + off);
    off += (bytes + 255) & ~(size_t)255;
    return p;
  };
  int* flags = (int*)alloc(2 * 4);
  int* cnt = (int*)alloc((size_t)N * 4);
  int* rowptr = (int*)alloc((size_t)(N + 1) * 4);
  int* fillp = (int*)alloc((size_t)N * 4);
  int* colb = (int*)alloc((size_t)E * 4);
  int* excl = (int*)alloc((size_t)N * 4);
  int* bsum = (int*)alloc(256 * 4);
  int* dmeta = (int*)alloc(128 * 4);   // dcnt[64] + dticket[64]
  uint4* perm4 = (uint4*)alloc((size_t)N * 16);
  u16* Wt1a = (u16*)alloc((size_t)128 * 128 * 2);
  u16* Wt1b = (u16*)alloc((size_t)128 * 128 * 2);
  u16* Wt1c = (u16*)alloc((size_t)128 * 128 * 2);
  u16* Wt2a = (u16*)alloc((size_t)256 * 128 * 2);
  u16* Wt2b = (u16*)alloc((size_t)256 * 128 * 2);
  u16* Wt2c = (u16*)alloc((size_t)256 * 128 * 2);
  u16* buf1 = (u16*)alloc((size_t)N * 256 * 2);
  u16* buf2 = (u16*)alloc((size_t)N * 256 * 2);
  u16* buf3 = (u16*)alloc((size_t)N * 256 * 2);
  u16* h1 = (u16*)alloc((size_t)N * 128 * 2);
  (void)ws_size; (void)n_in; (void)in_sizes; (void)out_size;

  int nb = (N + 255) / 256;
  int* dcnt = dmeta;
  int* dticket = dmeta + 64;

  probe_zero_kernel<<<nb, 256, 0, stream>>>(x16, ei, flags, cnt, dmeta, N);
  count_kernel<<<(E + 255) / 256, 256, 0, stream>>>(ei, flags, cnt, E);
  scan_local<<<nb, 256, 0, stream>>>(cnt, excl, bsum, dcnt, N);
  scan_add<<<nb, 256, 0, stream>>>(excl, bsum, cnt, rowptr, fillp, N, nb);
  deg_scatter<<<nb, 256, 0, stream>>>(cnt, rowptr, dcnt, dticket, perm4, N);
  fill_kernel<<<(E + 255) / 256, 256, 0, stream>>>(ei, flags, fillp, colb, E);
  transpose_w<<<dim3(128, 6), 256, 0, stream>>>(
      d_in[2], d_in[3], d_in[5], d_in[7], d_in[8], d_in[10],
      Wt1a, Wt1b, Wt1c, Wt2a, Wt2b, Wt2c, flags);

  int gx = (N + 63) / 64;
  gemm3_mz<1><<<dim3(gx, 3), 256, 0, stream>>>(
      d_in[0], Wt1a, Wt1b, Wt1c, d_in[6], buf1, buf2, buf3, flags, 1, N);
  gat_agg_kernel<128, true, 16><<<(N + 15) / 16, 256, 0, stream>>>(
      buf1, buf2, buf3, d_in[4], perm4, colb, h1, flags, 0, N);
  gemm3_mz<2><<<dim3(gx, 3), 256, 0, stream>>>(
      h1, Wt2a, Wt2b, Wt2c, d_in[11], buf1, buf2, buf3, flags, 0, N);
  gat_agg_kernel<256, false, 32><<<(N + 7) / 8, 256, 0, stream>>>(
      buf1, buf2, buf3, d_in[9], perm4, colb, d_out, flags, 1, N);
}